// Round 6
// baseline (95.888 us; speedup 1.0000x reference)
//
#include <hip/hip_runtime.h>

#define NB  16   // batch
#define NN  64   // nodes
#define NFD 64   // node features
#define EFD 5    // edge types
#define MFD 64   // message features

#define THREADS 256        // 4 waves
#define ROWS_PER_BLOCK 16  // 64 blocks = 16 b * 4 tiles
#define ROWS_PER_WAVE  4

__global__ __launch_bounds__(THREADS)
void ggnn_msgpass_kernel(const float* __restrict__ afm,    // (B,N,NF)
                         const int*   __restrict__ bfm,    // (B,N,N)
                         const int*   __restrict__ a_bfm,  // (B,N)
                         const float* __restrict__ adj_w,  // (EF,MF,NF)
                         const float* __restrict__ adj_a,  // (AEF,MF)
                         const float* __restrict__ bias,   // (MF)
                         float* __restrict__ out)          // (B,N,MF)
{
    __shared__ float afm_s[NN * NFD];                 // 16 KB
    __shared__ float W_s[EFD * MFD * NFD];            // 80 KB, f4-rotated rows
    __shared__ int   bfm_s[ROWS_PER_BLOCK * NN];      // 4 KB
    __shared__ float S_s[ROWS_PER_BLOCK][EFD][NFD];   // 20 KB

    const int t    = threadIdx.x;
    const int lane = t & 63;
    const int g    = t >> 6;             // wave id
    const int bx   = blockIdx.x;         // 64 blocks
    const int b    = bx >> 2;
    const int i0   = (bx & 3) * ROWS_PER_BLOCK;

    // ---- stage afm[b] (1024 f4), block-rotated start (channel spread) ----
    {
        const float4* src = (const float4*)(afm + (size_t)b * NN * NFD);
        float4*       dst = (float4*)afm_s;
        int c = (t + bx * 16) & 1023;
#pragma unroll
        for (int k = 0; k < 4; ++k) {
            dst[c] = src[c];
            c = (c + THREADS) & 1023;
        }
    }

    // ---- stage W (5120 f4), block-rotated start; per-row f4 rotation so
    //      phase-3 ds_read_b128 (lane=m) is bank-uniform ----
    {
        const float4* src = (const float4*)adj_w;
        float4*       dst = (float4*)W_s;
        int c = t + bx * 80;
        if (c >= 5120) c -= 5120;
#pragma unroll
        for (int k = 0; k < 20; ++k) {
            float4 w  = src[c];
            int row   = c >> 4;          // e*64 + m
            int m     = row & 63;
            int n4    = c & 15;
            dst[(row << 4) | ((n4 + m) & 15)] = w;
            c += THREADS;
            if (c >= 5120) c -= 5120;
        }
    }

    // ---- stage bfm rows i0..i0+15 (256 int4) ----
    {
        const int4* src = (const int4*)(bfm + (size_t)b * NN * NN + i0 * NN);
        ((int4*)bfm_s)[t] = src[t];
    }

    __syncthreads();

    // ---- phase 2: bucket-sum. wave g owns rows r0..r0+3; lane = n.
    // Edge type is wave-uniform per (row,j) -> scalar branch chain.
    {
        float acc[ROWS_PER_WAVE][EFD];
#pragma unroll
        for (int r = 0; r < ROWS_PER_WAVE; ++r)
#pragma unroll
            for (int e = 0; e < EFD; ++e) acc[r][e] = 0.f;

        const int r0 = g * ROWS_PER_WAVE;
        for (int j = 0; j < NN; ++j) {
            float v = afm_s[j * NFD + lane];
#pragma unroll
            for (int r = 0; r < ROWS_PER_WAVE; ++r) {
                int e = __builtin_amdgcn_readfirstlane(bfm_s[(r0 + r) * NN + j]);
                if      (e == 1) acc[r][0] += v;
                else if (e == 2) acc[r][1] += v;
                else if (e == 3) acc[r][2] += v;
                else if (e == 4) acc[r][3] += v;
                else if (e == 5) acc[r][4] += v;
            }
        }
#pragma unroll
        for (int r = 0; r < ROWS_PER_WAVE; ++r)
#pragma unroll
            for (int e = 0; e < EFD; ++e)
                S_s[r0 + r][e][lane] = acc[r][e];
    }

    __syncthreads();

    // ---- phase 3: wave g computes rows r0..r0+3; lane = m.
    // One W sweep (80 KB LDS, rotated b128, conflict-free) serves 4 rows;
    // S reads are uniform-address b128 broadcasts.
    {
        const int m  = lane;
        const int r0 = g * ROWS_PER_WAVE;
        float o0 = 0.f, o1 = 0.f, o2 = 0.f, o3 = 0.f;
        const float4* W4 = (const float4*)W_s;
#pragma unroll
        for (int e = 0; e < EFD; ++e) {
            const float4* s0 = (const float4*)&S_s[r0 + 0][e][0];
            const float4* s1 = (const float4*)&S_s[r0 + 1][e][0];
            const float4* s2 = (const float4*)&S_s[r0 + 2][e][0];
            const float4* s3 = (const float4*)&S_s[r0 + 3][e][0];
            const int wbase = (e * MFD + m) << 4;
#pragma unroll 4
            for (int n4 = 0; n4 < 16; ++n4) {
                float4 w  = W4[wbase | ((n4 + m) & 15)];
                float4 a0 = s0[n4];
                float4 a1 = s1[n4];
                float4 a2 = s2[n4];
                float4 a3 = s3[n4];
                o0 += w.x * a0.x + w.y * a0.y + w.z * a0.z + w.w * a0.w;
                o1 += w.x * a1.x + w.y * a1.y + w.z * a1.z + w.w * a1.w;
                o2 += w.x * a2.x + w.y * a2.y + w.z * a2.z + w.w * a2.w;
                o3 += w.x * a3.x + w.y * a3.y + w.z * a3.z + w.w * a3.w;
            }
        }

        // ---- epilogue: attention scale + bias, coalesced stores ----
        float ov[ROWS_PER_WAVE] = {o0, o1, o2, o3};
        const float bv = bias[m];
#pragma unroll
        for (int r = 0; r < ROWS_PER_WAVE; ++r) {
            int i  = i0 + r0 + r;
            int a  = a_bfm[b * NN + i];
            float att = (a > 0) ? adj_a[(a - 1) * MFD + m] : 0.f;
            out[((size_t)b * NN + i) * MFD + m] = ov[r] * att + bv;
        }
    }
}

extern "C" void kernel_launch(void* const* d_in, const int* in_sizes, int n_in,
                              void* d_out, int out_size, void* d_ws, size_t ws_size,
                              hipStream_t stream) {
    const float* afm   = (const float*)d_in[0];
    const int*   bfm   = (const int*)d_in[1];
    const int*   a_bfm = (const int*)d_in[2];
    const float* adj_w = (const float*)d_in[3];
    const float* adj_a = (const float*)d_in[4];
    const float* bias  = (const float*)d_in[5];
    float* out = (float*)d_out;

    dim3 grid(NB * 4);   // 64 blocks, 16 rows each
    dim3 block(THREADS);
    ggnn_msgpass_kernel<<<grid, block, 0, stream>>>(afm, bfm, a_bfm, adj_w,
                                                    adj_a, bias, out);
}

// Round 7
// 85.642 us; speedup vs baseline: 1.1196x; 1.1196x over previous
//
#include <hip/hip_runtime.h>

#define NB  16   // batch
#define NN  64   // nodes
#define NFD 64   // node features
#define EFD 5    // edge types
#define MFD 64   // message features
#define THREADS 256   // 4 waves; wave = one output row i

__global__ __launch_bounds__(THREADS)
void ggnn_msgpass_kernel(const float* __restrict__ afm,    // (B,N,NF)
                         const int*   __restrict__ bfm,    // (B,N,N)
                         const int*   __restrict__ a_bfm,  // (B,N)
                         const float* __restrict__ adj_w,  // (EF,MF,NF)
                         const float* __restrict__ adj_a,  // (AEF,MF)
                         const float* __restrict__ bias,   // (MF)
                         float* __restrict__ out)          // (B,N,MF)
{
    __shared__ float afm_s[NN * NFD];   // 16 KB only -> small LDS footprint

    const int t    = threadIdx.x;
    const int lane = t & 63;
    const int g    = t >> 6;            // wave id
    const int bx   = blockIdx.x;        // 256 blocks = 16 b * 16 tiles
    const int b    = bx >> 4;
    const int i    = ((bx & 15) << 2) + g;   // this wave's row

    // ---- stage afm[b] (1024 float4) coalesced; linear layout, reads later
    //      are row-broadcast + stride-1 (conflict-free) ----
    {
        const float4* src = (const float4*)(afm + (size_t)b * NN * NFD);
        float4*       dst = (float4*)afm_s;
#pragma unroll
        for (int k = 0; k < 4; ++k)
            dst[t + k * THREADS] = src[t + k * THREADS];
    }

    // ---- this wave's bfm row: lane j holds edge type (i,j); coalesced ----
    const int bfm_reg = bfm[((size_t)b * NN + i) * NN + lane];

    __syncthreads();

    // ---- phase 2: bucket sums S[e][n], lane = n. Branchless: e is wave-
    // uniform (readlane const-index after unroll) -> s_cselect + v_fmac ----
    float ac0 = 0.f, ac1 = 0.f, ac2 = 0.f, ac3 = 0.f, ac4 = 0.f;
#pragma unroll
    for (int j = 0; j < NN; ++j) {
        float v = afm_s[j * NFD + lane];
        int e = __builtin_amdgcn_readlane(bfm_reg, j);
        ac0 = fmaf((e == 1) ? 1.f : 0.f, v, ac0);
        ac1 = fmaf((e == 2) ? 1.f : 0.f, v, ac1);
        ac2 = fmaf((e == 3) ? 1.f : 0.f, v, ac2);
        ac3 = fmaf((e == 4) ? 1.f : 0.f, v, ac3);
        ac4 = fmaf((e == 5) ? 1.f : 0.f, v, ac4);
    }

    // ---- phase 3: p[m] = per-lane partial over n=lane:
    //      p[m] = sum_e W[e][m][lane] * S[e][lane]
    // W reads are lane-contiguous 256B (coalesced, L1/L2-resident) ----
    float p[MFD];
#pragma unroll
    for (int m = 0; m < MFD; ++m) {
        const float* wb = adj_w + (size_t)m * NFD + lane;
        float w0 = wb[0 * MFD * NFD];
        float w1 = wb[1 * MFD * NFD];
        float w2 = wb[2 * MFD * NFD];
        float w3 = wb[3 * MFD * NFD];
        float w4 = wb[4 * MFD * NFD];
        p[m] = w0 * ac0 + w1 * ac1 + w2 * ac2 + w3 * ac3 + w4 * ac4;
    }

    // ---- register butterfly transpose-reduce: 6 stages fold the m-dim into
    // the lane-dim; after stage s, p[m] (m<s) at lane L accumulates column
    // sums; final: lane L holds msg[i][m=L]. Verified mapping on 4-lane model.
#pragma unroll
    for (int s = 32; s >= 1; s >>= 1) {
#pragma unroll
        for (int m = 0; m < s; ++m) {
            float lo = p[m], hi = p[m + s];
            bool upper  = (lane & s) != 0;
            float mine  = upper ? hi : lo;
            float other = upper ? lo : hi;
            float recv  = __shfl_xor(other, s, 64);
            p[m] = mine + recv;
        }
    }
    float r = p[0];

    // ---- epilogue: attention scale + bias; coalesced store ----
    int a = a_bfm[b * NN + i];
    float att = (a > 0) ? adj_a[(size_t)(a - 1) * MFD + lane] : 0.f;
    out[((size_t)b * NN + i) * MFD + lane] = r * att + bias[lane];
}

extern "C" void kernel_launch(void* const* d_in, const int* in_sizes, int n_in,
                              void* d_out, int out_size, void* d_ws, size_t ws_size,
                              hipStream_t stream) {
    const float* afm   = (const float*)d_in[0];
    const int*   bfm   = (const int*)d_in[1];
    const int*   a_bfm = (const int*)d_in[2];
    const float* adj_w = (const float*)d_in[3];
    const float* adj_a = (const float*)d_in[4];
    const float* bias  = (const float*)d_in[5];
    float* out = (float*)d_out;

    dim3 grid(NB * (NN / 4));   // 256 blocks, 4 rows each (1 row/wave)
    dim3 block(THREADS);
    ggnn_msgpass_kernel<<<grid, block, 0, stream>>>(afm, bfm, a_bfm, adj_w,
                                                    adj_a, bias, out);
}

// Round 8
// 69.948 us; speedup vs baseline: 1.3708x; 1.2244x over previous
//
#include <hip/hip_runtime.h>

#define NB  16   // batch
#define NN  64   // nodes
#define NFD 64   // node features
#define EFD 5    // edge types
#define MFD 64   // message features
#define THREADS 256   // 4 waves; wave = one output row i

typedef const __attribute__((address_space(1))) void* gas_ptr;
typedef __attribute__((address_space(3))) void*       las_ptr;

__global__ __launch_bounds__(THREADS)
void ggnn_msgpass_kernel(const float* __restrict__ afm,    // (B,N,NF)
                         const int*   __restrict__ bfm,    // (B,N,N)
                         const int*   __restrict__ a_bfm,  // (B,N)
                         const float* __restrict__ adj_w,  // (EF,MF,NF)
                         const float* __restrict__ adj_a,  // (AEF,MF)
                         const float* __restrict__ bias,   // (MF)
                         float* __restrict__ out)          // (B,N,MF)
{
    __shared__ float afm_s[NN * NFD];        // 16 KB
    __shared__ float W_s[EFD * MFD * NFD];   // 80 KB, same layout as adj_w

    const int t    = threadIdx.x;
    const int lane = t & 63;
    const int g    = t >> 6;            // wave id
    const int bx   = blockIdx.x;        // 256 blocks = 16 b * 16 tiles
    const int b    = bx >> 4;
    const int i    = ((bx & 15) << 2) + g;   // this wave's row

    // ---- bulk async global->LDS DMA: 24 fire-and-forget issues per wave,
    // all outstanding at once -> ONE HBM latency round (caches are wiped by
    // the harness's 256MB poison every iteration; serial misses were the
    // 37us). LDS dest is wave-uniform base + lane*16 (linear), global src
    // per-lane contiguous: perfectly coalesced 1KB per issue.
    {
        const float4* wsrc = (const float4*)adj_w;              // 5120 f4
#pragma unroll
        for (int k = 0; k < 20; ++k) {
            int q = g * 20 + k;                                 // wave-uniform
            __builtin_amdgcn_global_load_lds((gas_ptr)(wsrc + q * 64 + lane),
                                             (las_ptr)(W_s + q * 256),
                                             16, 0, 0);
        }
        const float4* asrc = (const float4*)(afm + (size_t)b * NN * NFD);
#pragma unroll
        for (int k = 0; k < 4; ++k) {
            int q = g * 4 + k;
            __builtin_amdgcn_global_load_lds((gas_ptr)(asrc + q * 64 + lane),
                                             (las_ptr)(afm_s + q * 256),
                                             16, 0, 0);
        }
    }

    // ---- independent small loads, issued under the DMA shadow ----
    const int   bfm_reg = bfm[((size_t)b * NN + i) * NN + lane]; // lane j = type(i,j)
    const int   a       = a_bfm[b * NN + i];
    const float bv      = bias[lane];

    __syncthreads();   // compiler emits s_waitcnt vmcnt(0) lgkmcnt(0) + s_barrier

    // att depends on `a` (arrived by now); its latency overlaps phases 2-3
    const float att = (a > 0) ? adj_a[(size_t)(a - 1) * MFD + lane] : 0.f;

    // ---- phase 2: bucket sums, lane = n. Branchless: e wave-uniform
    // (readlane const-index after unroll) -> s_cselect + v_fmac ----
    float ac0 = 0.f, ac1 = 0.f, ac2 = 0.f, ac3 = 0.f, ac4 = 0.f;
#pragma unroll
    for (int j = 0; j < NN; ++j) {
        float v = afm_s[j * NFD + lane];
        int e = __builtin_amdgcn_readlane(bfm_reg, j);
        ac0 = fmaf((e == 1) ? 1.f : 0.f, v, ac0);
        ac1 = fmaf((e == 2) ? 1.f : 0.f, v, ac1);
        ac2 = fmaf((e == 3) ? 1.f : 0.f, v, ac2);
        ac3 = fmaf((e == 4) ? 1.f : 0.f, v, ac3);
        ac4 = fmaf((e == 5) ? 1.f : 0.f, v, ac4);
    }

    // ---- phase 3: p[m] = sum_e W[e][m][lane] * ac[e], W from LDS.
    // ds_read_b32, lanes consecutive (stride 4B) -> 2 lanes/bank, free ----
    float p[MFD];
#pragma unroll
    for (int m = 0; m < MFD; ++m) {
        const float* wb = W_s + (size_t)m * NFD + lane;
        float w0 = wb[0 * MFD * NFD];
        float w1 = wb[1 * MFD * NFD];
        float w2 = wb[2 * MFD * NFD];
        float w3 = wb[3 * MFD * NFD];
        float w4 = wb[4 * MFD * NFD];
        p[m] = w0 * ac0 + w1 * ac1 + w2 * ac2 + w3 * ac3 + w4 * ac4;
    }

    // ---- register butterfly transpose-reduce (verified R7): 6 stages fold
    // the m-dim into the lane-dim; final: lane L holds msg[i][m=L] ----
#pragma unroll
    for (int s = 32; s >= 1; s >>= 1) {
#pragma unroll
        for (int m = 0; m < s; ++m) {
            float lo = p[m], hi = p[m + s];
            bool upper  = (lane & s) != 0;
            float mine  = upper ? hi : lo;
            float other = upper ? lo : hi;
            float recv  = __shfl_xor(other, s, 64);
            p[m] = mine + recv;
        }
    }
    float r = p[0];

    // ---- epilogue: attention scale + bias; coalesced store ----
    out[((size_t)b * NN + i) * MFD + lane] = r * att + bv;
}

extern "C" void kernel_launch(void* const* d_in, const int* in_sizes, int n_in,
                              void* d_out, int out_size, void* d_ws, size_t ws_size,
                              hipStream_t stream) {
    const float* afm   = (const float*)d_in[0];
    const int*   bfm   = (const int*)d_in[1];
    const int*   a_bfm = (const int*)d_in[2];
    const float* adj_w = (const float*)d_in[3];
    const float* adj_a = (const float*)d_in[4];
    const float* bias  = (const float*)d_in[5];
    float* out = (float*)d_out;

    dim3 grid(NB * (NN / 4));   // 256 blocks, 4 rows each (1 row/wave)
    dim3 block(THREADS);
    ggnn_msgpass_kernel<<<grid, block, 0, stream>>>(afm, bfm, a_bfm, adj_w,
                                                    adj_a, bias, out);
}